// Round 15
// baseline (138.467 us; speedup 1.0000x reference)
//
#include <hip/hip_runtime.h>
#include <math.h>

// GEBLNet via Gram-matrix reduction (R15 = R14 + 2a overhead cuts).
//   T[u] = sum_{v,w} w2[u,v,w] * tr(We2[v] @ We2[w]) -> 169 unique Gram values,
//   w2 folded per-launch into CTt[169][12] float4 (setup kernel; ~40us
//   bench-vs-main gap is fixed harness overhead, extra dispatch is free).
// Shape (R10/R14-proven): 8192 blocks x 64 threads, 1 wave = 1 point.
// Layer 1 on all 64 lanes, two u-half passes through a small LDS B buffer:
//   2a: job=(uu,v,g3) triple: B[uu,v,3g3+j] = sum_w w1[u0+uu,v,w]*We[w,3g3+j]
//       234 jobs/pass, <=4/lane, 3 reg accumulators, 13 VMEM/job (was 1/cmac).
//   2b: H[u0+uu,ik] = sum_{v,j} We[v,i,j]*B[uu,v,j*3+k]  (54 jobs, 39 cmacs)
// R15 fixes vs R14 (82us main, 2.69M bank conflicts, ~3x inst overhead/FMA):
//   - Bs row pad 10 -> 11 float2 (stride 22 words, gcd(22,32)=2: 2-way = free;
//     stride 20 words had gcd 4 -> 8-way conflicts on 2a writes).
//   - jk-triple mapping: VMEM 286->~104/lane, decodes 22->8.
// LESSON (R13): VGPR>64 costs ~40% occupancy here; keep w-loop unroll 1.
// LESSON (R12): multi-wave blocks regress. LESSON (R11): direct-w2 regresses.
// LESSON (R4+R7): launch_bounds min-waves arg -> spill. LESSON (R6): never
// reinterpret-cast local arrays.

#define NPTS 8192
#define THRESH 0.001f

__global__ void geblnet_setup(const float* __restrict__ w2,
                              float4* __restrict__ CTt) {
    int j = blockIdx.x * blockDim.x + threadIdx.x;
    if (j >= 12 * 169) return;
    int u = j / 169, it = j % 169;
    const float* W = w2 + u * 25 * 25 * 2;
#define WR(v, w) W[((v) * 25 + (w)) * 2]
#define WI(v, w) W[((v) * 25 + (w)) * 2 + 1]
    float c0, c1, c2, c3;
    if (it < 78) {                       // S pairs, a<=b
        int q = it, a = 0;
        while (q >= 12 - a) { q -= 12 - a; ++a; }
        int b = a + q;
        float ar = WR(a, b) + (a != b ? WR(b, a) : 0.f);
        float ai = WI(a, b) + (a != b ? WI(b, a) : 0.f);
        float br = WR(12 + a, 12 + b) + (a != b ? WR(12 + b, 12 + a) : 0.f);
        float bi = WI(12 + a, 12 + b) + (a != b ? WI(12 + b, 12 + a) : 0.f);
        c0 = ar + br; c1 = bi - ai; c2 = ai + bi; c3 = ar - br;
    } else if (it < 156) {               // Hm pairs, a<=b
        int q = it - 78, a = 0;
        while (q >= 12 - a) { q -= 12 - a; ++a; }
        int b = a + q;
        if (a != b) {
            float gr = WR(a, 12 + b) + WR(12 + b, a);
            float gi = WI(a, 12 + b) + WI(12 + b, a);
            float dr = WR(b, 12 + a) + WR(12 + a, b);
            float di = WI(b, 12 + a) + WI(12 + a, b);
            c0 = gr + dr; c1 = di - gi; c2 = gi + di; c3 = gr - dr;
        } else {
            float er = WR(a, 12 + a) + WR(12 + a, a);
            float ei = WI(a, 12 + a) + WI(12 + a, a);
            c0 = er; c1 = 0.f; c2 = ei; c3 = 0.f;
        }
    } else if (it < 168) {               // trace terms
        int a = it - 156;
        float fr = WR(a, 24) + WR(24, a), fi = WI(a, 24) + WI(24, a);
        float pr = WR(12 + a, 24) + WR(24, 12 + a);
        float pi = WI(12 + a, 24) + WI(24, 12 + a);
        c0 = fr + pr; c1 = pi - fi; c2 = fi + pi; c3 = fr - pr;
    } else {                             // unit-unit
        c0 = 3.f * WR(24, 24); c1 = 0.f; c2 = 3.f * WI(24, 24); c3 = 0.f;
    }
    CTt[it * 12 + u] = make_float4(c0, c1, c2, c3);
#undef WR
#undef WI
}

__global__ __launch_bounds__(64) void geblnet_main(
    const float2* __restrict__ x2,      // (8192, 10, 9) complex
    const float2* __restrict__ w1g,     // (12,13,13) complex
    const float* __restrict__ dw,       // (24,)
    const float* __restrict__ db,       // (1,)
    const float4* __restrict__ CTt,     // (169,12)
    float* __restrict__ out)            // (8192,)
{
    // Overlay: phases 1-2 = We row-major (13 ch incl. identity, stride 10);
    //          phases 4-5 = GV[169].
    __shared__ float2 WeGV[170];        // 1360 B
    __shared__ float2 Bs[858];          // 6864 B: B[uu][v][jk], rows pad 11
    __shared__ float2 Hs[108];          //  864 B
    __shared__ float2 Tpar[60];         //  480 B
    __shared__ float2 tr1[12];          //   96 B
    __shared__ float  sc1[12];          //   48 B
    __shared__ float  gb[12];           //   48 B
    __shared__ float  tra[12];          //   48 B

    const int t = threadIdx.x;
    const int p = blockIdx.x;

    // ---- phase 1: build We channels 0..12 (12 data + identity), stride 10
    for (int j = t; j < 117; j += 64) {
        int v = j / 9, ik = j - v * 9;
        int i = ik / 3, jj = ik - i * 3;
        float2 val;
        if (v < 6) val = x2[(size_t)p * 90 + (4 + v) * 9 + ik];
        else if (v < 12) {
            float2 s = x2[(size_t)p * 90 + (v - 2) * 9 + jj * 3 + i];
            val = make_float2(s.x, -s.y);
        } else val = make_float2((i == jj) ? 1.f : 0.f, 0.f);
        WeGV[v * 10 + ik] = val;
    }
    __syncthreads();

    // ---- phase 2: layer 1 on all 64 lanes, two u-half passes
    #pragma unroll 1
    for (int g = 0; g < 2; ++g) {
        const int u0 = g * 6;
        // 2a: job=(uu,v,g3): B[uu,v,3g3+j] = sum_w w1[u0+uu,v,w]*We[w,3g3+j]
        #pragma unroll 1
        for (int e = t; e < 234; e += 64) {
            int uu = e / 39, rem = e - uu * 39;
            int v = rem / 3, g3 = rem - v * 3;
            const float2* cp = w1g + ((u0 + uu) * 13 + v) * 13;
            const float2* wep = &WeGV[g3 * 3];
            float b0r = 0.f, b0i = 0.f, b1r = 0.f, b1i = 0.f, b2r = 0.f, b2i = 0.f;
            #pragma unroll 1
            for (int w = 0; w < 13; ++w) {
                float2 cc = cp[w];
                float2 e0 = wep[w * 10 + 0];
                float2 e1 = wep[w * 10 + 1];
                float2 e2 = wep[w * 10 + 2];
                b0r += cc.x * e0.x - cc.y * e0.y;  b0i += cc.x * e0.y + cc.y * e0.x;
                b1r += cc.x * e1.x - cc.y * e1.y;  b1i += cc.x * e1.y + cc.y * e1.x;
                b2r += cc.x * e2.x - cc.y * e2.y;  b2i += cc.x * e2.y + cc.y * e2.x;
            }
            float2* bp = &Bs[(uu * 13 + v) * 11 + g3 * 3];
            bp[0] = make_float2(b0r, b0i);
            bp[1] = make_float2(b1r, b1i);
            bp[2] = make_float2(b2r, b2i);
        }
        __syncthreads();
        // 2b: H[u0+uu][i][k] = sum_{v,j} We[v][i][j] * B[uu][v][j*3+k]
        if (t < 54) {
            int uu = t / 9, ik = t - uu * 9;
            int i = ik / 3, k = ik - i * 3;
            float hr = 0.f, hi = 0.f;
            #pragma unroll
            for (int v = 0; v < 13; ++v) {
                const float2* a = &WeGV[v * 10 + i * 3];
                const float2* b = &Bs[(uu * 13 + v) * 11 + k];
                #pragma unroll
                for (int j = 0; j < 3; ++j) {
                    float2 aj = a[j];
                    float2 bj = b[j * 3];
                    hr += aj.x * bj.x - aj.y * bj.y;
                    hi += aj.x * bj.y + aj.y * bj.x;
                }
            }
            Hs[(u0 + uu) * 9 + ik] = make_float2(hr, hi);
        }
        __syncthreads();
    }

    // ---- phase 3: traces + gerelu + trnorm scales
    if (t < 12) {
        float2 a = Hs[t * 9 + 0], b = Hs[t * 9 + 4], c = Hs[t * 9 + 8];
        float2 tt = make_float2(a.x + b.x + c.x, a.y + b.y + c.y);
        tr1[t] = tt;
        float gg = tt.x > 0.f ? tt.x : 0.f;
        gb[t] = gg;
        tra[t] = gg * sqrtf(tt.x * tt.x + tt.y * tt.y);
    }
    __syncthreads();
    if (t < 12) {
        float m = 0.f;
        #pragma unroll
        for (int u = 0; u < 12; ++u) m += tra[u];
        sc1[t] = gb[t] / fmaxf(m * (1.f / 12.f), THRESH);
    }
    __syncthreads();

    // ---- phase 4: Gram values -> GV (overlays We row-major; dead now)
    for (int it = t; it < 169; it += 64) {
        float2 val;
        if (it < 156) {
            int q = it < 78 ? it : it - 78;
            float fs = sqrtf(625.0f - 8.0f * (float)q);   // exact at bucket edges
            int a = (int)((25.0f - fs) * 0.5f);
            int b = q - (a * (25 - a)) / 2 + a;
            const float2* Ha = &Hs[a * 9];
            const float2* Hb = &Hs[b * 9];
            float s = sc1[a] * sc1[b];
            float vr = 0.f, vi = 0.f;
            if (it < 78) {                    // S = tr(Aa Ab)
                #pragma unroll
                for (int i = 0; i < 3; ++i)
                    #pragma unroll
                    for (int jj = 0; jj < 3; ++jj) {
                        float2 A = Ha[i * 3 + jj], B = Hb[jj * 3 + i];
                        vr += A.x * B.x - A.y * B.y;
                        vi += A.x * B.y + A.y * B.x;
                    }
            } else {                          // Hm = tr(Aa Ab^H)
                #pragma unroll
                for (int e = 0; e < 9; ++e) {
                    float2 A = Ha[e], B = Hb[e];
                    vr += A.x * B.x + A.y * B.y;
                    vi += A.y * B.x - A.x * B.y;
                }
            }
            val = make_float2(s * vr, s * vi);
        } else if (it < 168) {
            int a = it - 156;
            float s = sc1[a]; float2 tt = tr1[a];
            val = make_float2(s * tt.x, s * tt.y);
        } else {
            val = make_float2(1.f, 0.f);
        }
        WeGV[it] = val;
    }
    __syncthreads();

    // ---- phase 5: coefficient contraction, lane=(q,u), 60 active
    if (t < 60) {
        int q = t / 12, u = t - q * 12;
        int i0 = q * 34, i1 = (q == 4) ? 169 : i0 + 34;
        float tre = 0.f, tim = 0.f;
        for (int it = i0; it < i1; ++it) {
            float4 c = CTt[it * 12 + u];
            float2 gv = WeGV[it];
            tre += c.x * gv.x + c.y * gv.y;
            tim += c.z * gv.x + c.w * gv.y;
        }
        Tpar[u * 5 + q] = make_float2(tre, tim);
    }
    __syncthreads();

    // ---- phase 6: layer-2 gerelu + trnorm + dense head
    if (t < 12) {
        float2 tt = make_float2(0.f, 0.f);
        #pragma unroll
        for (int q = 0; q < 5; ++q) {
            float2 A = Tpar[t * 5 + q];
            tt.x += A.x; tt.y += A.y;
        }
        tr1[t] = tt;
        float g = tt.x > 0.f ? tt.x : 0.f;
        gb[t] = g;
        tra[t] = g * sqrtf(tt.x * tt.x + tt.y * tt.y);
    }
    __syncthreads();
    if (t == 0) {
        float m = 0.f;
        #pragma unroll
        for (int u = 0; u < 12; ++u) m += tra[u];
        float inv = 1.f / fmaxf(m * (1.f / 12.f), THRESH);
        float acc = db[0];
        #pragma unroll
        for (int u = 0; u < 12; ++u) {
            float s = gb[u] * inv * (1.f / 3.f);
            acc += s * (tr1[u].x * dw[2 * u] + tr1[u].y * dw[2 * u + 1]);
        }
        out[p] = acc;
    }
}

extern "C" void kernel_launch(void* const* d_in, const int* in_sizes, int n_in,
                              void* d_out, int out_size, void* d_ws, size_t ws_size,
                              hipStream_t stream) {
    const float* x  = (const float*)d_in[0];
    const float* w1 = (const float*)d_in[1];
    const float* w2 = (const float*)d_in[2];
    const float* dw = (const float*)d_in[3];
    const float* db = (const float*)d_in[4];
    float* outp = (float*)d_out;
    float4* CTt = (float4*)d_ws;          // 12*169*16 B = 32448 B

    geblnet_setup<<<(12 * 169 + 255) / 256, 256, 0, stream>>>(w2, CTt);

    geblnet_main<<<NPTS, 64, 0, stream>>>(
        (const float2*)x, (const float2*)w1, dw, db, CTt, outp);
}